// Round 1
// baseline (625.345 us; speedup 1.0000x reference)
//
#include <hip/hip_runtime.h>

#define BB 256
#define TT 1024
#define II 3
#define HH 128
#define OO 3
#define NT 320   // 4 compute waves (256 thr) + 1 store/projection wave (64 thr)

#if __has_builtin(__builtin_amdgcn_exp2f)
#define EXP2F __builtin_amdgcn_exp2f
#else
#define EXP2F exp2f
#endif
#if __has_builtin(__builtin_amdgcn_rcpf)
#define RCPF __builtin_amdgcn_rcpf
#else
#define RCPF(x) (1.0f / (x))
#endif

// tanh(x) = 1 - 2/(e^{2x}+1)
__device__ __forceinline__ float fast_tanh(float x) {
    float e = EXP2F(x * 2.885390081777927f);
    return 1.0f - 2.0f * RCPF(e + 1.0f);
}

// Workgroup barrier that fences LDS only — does NOT drain vmcnt, so global
// stores stay in flight across it. All cross-wave dataflow goes through LDS.
__device__ __forceinline__ void bar_lds() {
    asm volatile("s_waitcnt lgkmcnt(0)\n\ts_barrier" ::: "memory");
}

// s[lane] + s[lane^32] via v_permlane32_swap_b32 (VALU, ~5cyc) instead of a
// ds_bpermute (~50-60cyc LDS-pipe op). a+b is orientation-agnostic: the swap
// exchanges 32-lane halves between the two registers, so whatever lands in
// a/b, their per-lane sum is s[lane] + s[lane^32]. Early-clobber forces
// distinct registers (a==b would self-swap and double-count).
__device__ __forceinline__ float xor32_sum(float s) {
    float a = s, b = s;
    asm("v_permlane32_swap_b32 %0, %1" : "+&v"(a), "+&v"(b));
    return a + b;
}

// sum over 4-lane quad via DPP quad_perm (pure VALU, no LDS pipe)
__device__ __forceinline__ float quad_reduce(float p) {
    p += __uint_as_float(__builtin_amdgcn_update_dpp(
        0, (int)__float_as_uint(p), 0xB1, 0xF, 0xF, true));  // xor 1: [1,0,3,2]
    p += __uint_as_float(__builtin_amdgcn_update_dpp(
        0, (int)__float_as_uint(p), 0x4E, 0xF, 0xF, true));  // xor 2: [2,3,0,1]
    return p;
}

// One block per batch element. One s_barrier per timestep. Latency-bound:
// wall time = 1024 * per-step critical path, so everything serial in the
// step window is minimized.
// Waves 0-3: wave wv owns outputs h = 32*wv .. 32*wv+31; sub = lane>>5 picks
//   interleaved float4 K-chunks (2j+sub); reduce = one permlane32 (VALU).
// Wave 4: hid/out stores, projection pipelined across 2 barrier windows:
//   A(t): 2 MACs + DPP quad-reduce -> 16 partials to LDS scratch (dbuf)
//   B(t): 3 lanes sum 16 partials from *previous* window -> out[t-2]
__global__ __launch_bounds__(NT) void rnn_kernel(
    const float* __restrict__ x,     // [B,T,I]
    const float* __restrict__ Wih,   // [H,I]
    const float* __restrict__ Whh,   // [H,H]
    const float* __restrict__ bih,   // [H]
    const float* __restrict__ bhh,   // [H]
    const float* __restrict__ h0,    // [1,H]
    const float* __restrict__ Wout,  // [O,H]
    const float* __restrict__ bout,  // [O]
    float* __restrict__ out,         // [B,T,O]
    float* __restrict__ hid)         // [B,T,H]
{
    __shared__ __align__(16) float4 xs[TT];       // (x0,x1,x2,pad) per t
    __shared__ __align__(16) float hbuf[2][HH];   // double-buffered hidden
    __shared__ __align__(16) float psum[2][OO * 16];  // projection partials

    const int tid = threadIdx.x;
    const int b = blockIdx.x;

    // --- stage inputs; init h(0) ---
    const float* xb = x + (size_t)b * TT * II;
    for (int idx = tid; idx < TT * II; idx += NT) {
        int t = idx / 3;
        int c = idx - t * 3;
        ((float*)&xs[t])[c] = xb[idx];
    }
    if (tid < HH) hbuf[0][tid] = h0[tid];

    if (tid < 256) {
        // ================= compute waves =================
        const int lane = tid & 63;
        const int wv   = tid >> 6;       // wave 0..3
        const int o32  = lane & 31;      // output within wave's 32
        const int sub  = lane >> 5;      // K-half 0..1 (interleaved float4s)
        const int h    = wv * 32 + o32;  // global output index

        // W_hh[h][k] for k-chunks c = 2j+sub (float4 granularity), j=0..15
        float w[64];
        {
            const float4* wrow = (const float4*)(Whh + h * HH);
#pragma unroll
            for (int j = 0; j < 16; j++) {
                float4 v = wrow[2 * j + sub];
                w[4*j+0] = v.x; w[4*j+1] = v.y; w[4*j+2] = v.z; w[4*j+3] = v.w;
            }
        }
        const float wi0 = Wih[h * II + 0];
        const float wi1 = Wih[h * II + 1];
        const float wi2 = Wih[h * II + 2];
        const float bias = bih[h] + bhh[h];

        const float4* hr0 = (const float4*)hbuf[0] + sub;  // read base, even t
        const float4* hr1 = (const float4*)hbuf[1] + sub;  // read base, odd t
        float* hw0 = &hbuf[1][h];  // write target when reading hbuf[0]
        float* hw1 = &hbuf[0][h];

        bar_lds();

        auto cstep = [&](int t, const float4* hr, float* hw) {
            float a0 = 0.f, a1 = 0.f, a2 = 0.f, a3 = 0.f;
            if (sub == 0) {
                float4 xv = xs[t];  // broadcast
                a0 = fmaf(xv.x, wi0, bias);
                a0 = fmaf(xv.y, wi1, a0);
                a0 = fmaf(xv.z, wi2, a0);
            }
            // 16 ds_read_b128; the wave's two distinct addrs per issue are
            // adjacent 16B chunks -> disjoint banks, 32-lane broadcast each.
#pragma unroll
            for (int j = 0; j < 16; j++) {
                float4 hh = hr[2 * j];
                a0 = fmaf(w[4*j+0], hh.x, a0);
                a1 = fmaf(w[4*j+1], hh.y, a1);
                a2 = fmaf(w[4*j+2], hh.z, a2);
                a3 = fmaf(w[4*j+3], hh.w, a3);
            }
            float s = xor32_sum((a0 + a1) + (a2 + a3));
            float th = fast_tanh(s);
            if (sub == 0) *hw = th;
            bar_lds();
        };

        for (int t = 0; t < TT; t += 2) {
            cstep(t, hr0, hw0);
            cstep(t + 1, hr1, hw1);
        }
    } else {
        // ================= store + projection wave =================
        const int L = tid - 256;  // lane 0..63; owns h = 2L, 2L+1
        const float w00 = Wout[0 * HH + 2 * L], w01 = Wout[0 * HH + 2 * L + 1];
        const float w10 = Wout[1 * HH + 2 * L], w11 = Wout[1 * HH + 2 * L + 1];
        const float w20 = Wout[2 * HH + 2 * L], w21 = Wout[2 * HH + 2 * L + 1];
        const float bL = (L == 0) ? bout[0] : (L == 1) ? bout[1]
                       : (L == 2) ? bout[2] : 0.f;
        float* ob = out + (size_t)b * TT * OO;
        float* hb = hid + (size_t)b * TT * HH;
        const int q = L >> 2;               // quad id 0..15 (h-range 8q..8q+7)
        const bool qlead = (L & 3) == 0;

        bar_lds();

        auto sstep = [&](int t, const float* hcur, float* psA, const float* psB) {
            // phase A: hid[t-1] store + quad partials for out[t-1] -> psA
            if (t >= 1) {
                const float2 hv = ((const float2*)hcur)[L];
                ((float2*)(hb + (size_t)(t - 1) * HH))[L] = hv;  // coalesced 512B
                float p0 = fmaf(hv.x, w00, hv.y * w01);
                float p1 = fmaf(hv.x, w10, hv.y * w11);
                float p2 = fmaf(hv.x, w20, hv.y * w21);
                p0 = quad_reduce(p0);
                p1 = quad_reduce(p1);
                p2 = quad_reduce(p2);
                if (qlead) {
                    psA[0 * 16 + q] = p0;
                    psA[1 * 16 + q] = p1;
                    psA[2 * 16 + q] = p2;
                }
            }
            // phase B: finish out[t-2] from previous window's partials (psB).
            // Same-wave producer/consumer, no extra sync needed.
            if (t >= 2 && L < OO) {
                const float4* pp = (const float4*)(psB + L * 16);
                float4 u0 = pp[0], u1 = pp[1], u2 = pp[2], u3 = pp[3];
                float s0 = ((u0.x + u0.y) + (u0.z + u0.w)) +
                           ((u1.x + u1.y) + (u1.z + u1.w));
                float s1 = ((u2.x + u2.y) + (u2.z + u2.w)) +
                           ((u3.x + u3.y) + (u3.z + u3.w));
                ob[(size_t)(t - 2) * OO + L] = s0 + s1 + bL;
            }
            bar_lds();
        };

        for (int t = 0; t < TT; t += 2) {
            sstep(t, hbuf[0], psum[0], psum[1]);
            sstep(t + 1, hbuf[1], psum[1], psum[0]);
        }

        // tail (no barriers; compute waves have exited, barrier counts match):
        // hbuf[0] = h[TT-1], psum[1] holds partials for out[TT-2].
        {
            const float2 hv = ((const float2*)hbuf[0])[L];
            ((float2*)(hb + (size_t)(TT - 1) * HH))[L] = hv;
            float p0 = fmaf(hv.x, w00, hv.y * w01);
            float p1 = fmaf(hv.x, w10, hv.y * w11);
            float p2 = fmaf(hv.x, w20, hv.y * w21);
            p0 = quad_reduce(p0);
            p1 = quad_reduce(p1);
            p2 = quad_reduce(p2);
            if (qlead) {
                psum[0][0 * 16 + q] = p0;
                psum[0][1 * 16 + q] = p1;
                psum[0][2 * 16 + q] = p2;
            }
            if (L < OO) {
                const float4* pp = (const float4*)(psum[1] + L * 16);
                float4 u0 = pp[0], u1 = pp[1], u2 = pp[2], u3 = pp[3];
                float s0 = ((u0.x + u0.y) + (u0.z + u0.w)) +
                           ((u1.x + u1.y) + (u1.z + u1.w));
                float s1 = ((u2.x + u2.y) + (u2.z + u2.w)) +
                           ((u3.x + u3.y) + (u3.z + u3.w));
                ob[(size_t)(TT - 2) * OO + L] = s0 + s1 + bL;
                // out[TT-1]: psum[0] written above by this same wave; DS ops
                // from one wave execute in program order.
                const float4* pq = (const float4*)(psum[0] + L * 16);
                float4 v0 = pq[0], v1 = pq[1], v2 = pq[2], v3 = pq[3];
                float r0 = ((v0.x + v0.y) + (v0.z + v0.w)) +
                           ((v1.x + v1.y) + (v1.z + v1.w));
                float r1 = ((v2.x + v2.y) + (v2.z + v2.w)) +
                           ((v3.x + v3.y) + (v3.z + v3.w));
                ob[(size_t)(TT - 1) * OO + L] = r0 + r1 + bL;
            }
        }
    }
}

extern "C" void kernel_launch(void* const* d_in, const int* in_sizes, int n_in,
                              void* d_out, int out_size, void* d_ws, size_t ws_size,
                              hipStream_t stream) {
    const float* x    = (const float*)d_in[0];  // [256,1024,3]
    const float* Wih  = (const float*)d_in[1];  // [128,3]
    const float* Whh  = (const float*)d_in[2];  // [128,128]
    const float* bih  = (const float*)d_in[3];  // [128]
    const float* bhh  = (const float*)d_in[4];  // [128]
    const float* h0   = (const float*)d_in[5];  // [1,128]
    const float* Wout = (const float*)d_in[6];  // [3,128]
    const float* bout = (const float*)d_in[7];  // [3]

    float* out = (float*)d_out;                 // [B,T,O] first
    float* hid = out + (size_t)BB * TT * OO;    // then [B,T,H]

    rnn_kernel<<<BB, NT, 0, stream>>>(x, Wih, Whh, bih, bhh, h0, Wout, bout, out, hid);
}

// Round 2
// 468.808 us; speedup vs baseline: 1.3339x; 1.3339x over previous
//
#include <hip/hip_runtime.h>

#define BB 256
#define TT 1024
#define II 3
#define HH 128
#define OO 3
#define NT 576   // 8 compute waves (512 thr) + 1 store/projection wave (64 thr)

#if __has_builtin(__builtin_amdgcn_exp2f)
#define EXP2F __builtin_amdgcn_exp2f
#else
#define EXP2F exp2f
#endif
#if __has_builtin(__builtin_amdgcn_rcpf)
#define RCPF __builtin_amdgcn_rcpf
#else
#define RCPF(x) (1.0f / (x))
#endif

// tanh(x) = 1 - 2/(e^{2x}+1)
__device__ __forceinline__ float fast_tanh(float x) {
    float e = EXP2F(x * 2.885390081777927f);
    return 1.0f - 2.0f * RCPF(e + 1.0f);
}

// Workgroup barrier that fences LDS only — does NOT drain vmcnt, so global
// stores stay in flight across it. All cross-wave dataflow goes through LDS.
__device__ __forceinline__ void bar_lds() {
    asm volatile("s_waitcnt lgkmcnt(0)\n\ts_barrier" ::: "memory");
}

// p += p(lane ^ pattern) via DPP (pure VALU; keeps the reduce off the LDS pipe)
template <int CTRL>
__device__ __forceinline__ float dpp_add(float p) {
    return p + __uint_as_float(__builtin_amdgcn_update_dpp(
        0, (int)__float_as_uint(p), CTRL, 0xF, 0xF, true));
}
#define DPP_XOR1 0xB1   // quad_perm [1,0,3,2]
#define DPP_XOR2 0x4E   // quad_perm [2,3,0,1]
#define DPP_HALF_MIRROR 0x141  // lane -> lane^7 within 8-lane half-rows

// sum over 4-lane quad via DPP quad_perm (store wave)
__device__ __forceinline__ float quad_reduce(float p) {
    p = dpp_add<DPP_XOR1>(p);
    p = dpp_add<DPP_XOR2>(p);
    return p;
}

// One block per batch element; one s_barrier per timestep (latency-bound:
// wall time = 1024 * per-step critical path).
//
// Compute: 8 waves. Wave wv, lane l: g = l>>3, s = l&7.
//   Lane computes BOTH outputs o0 = 2*(8*wv+g), o0+1 over K-chunk
//   [16s, 16s+16) — each h-chunk read feeds 2 outputs, halving LDS
//   broadcast traffic vs 1-output-per-lane (32KB/step instead of 64KB).
//   K-split-8 reduce is DPP-only: xor1, xor2 (quads), then half_mirror
//   (lane^7, crosses quads) -> all 8 lanes hold the full sum.
//   float4 read order swizzled by j' = (j + (s>>1)) & 3 (weights loaded in
//   matching order) so the 8 distinct 16B chunks per ds_read_b128 hit 8
//   distinct bank groups.
// Wave 8: hid/out stores, projection pipelined across 2 barrier windows
//   (phase A: MACs + DPP quad-reduce -> LDS partials; phase B next window).
__global__ __launch_bounds__(NT) void rnn_kernel(
    const float* __restrict__ x,     // [B,T,I]
    const float* __restrict__ Wih,   // [H,I]
    const float* __restrict__ Whh,   // [H,H]
    const float* __restrict__ bih,   // [H]
    const float* __restrict__ bhh,   // [H]
    const float* __restrict__ h0,    // [1,H]
    const float* __restrict__ Wout,  // [O,H]
    const float* __restrict__ bout,  // [O]
    float* __restrict__ out,         // [B,T,O]
    float* __restrict__ hid)         // [B,T,H]
{
    __shared__ __align__(16) float4 xs[TT];       // (x0,x1,x2,pad) per t
    __shared__ __align__(16) float hbuf[2][HH];   // double-buffered hidden
    __shared__ __align__(16) float psum[2][OO * 16];  // projection partials

    const int tid = threadIdx.x;
    const int b = blockIdx.x;

    // --- stage inputs; init h(0) ---
    const float* xb = x + (size_t)b * TT * II;
    for (int idx = tid; idx < TT * II; idx += NT) {
        int t = idx / 3;
        int c = idx - t * 3;
        ((float*)&xs[t])[c] = xb[idx];
    }
    if (tid < HH) hbuf[0][tid] = h0[tid];

    if (tid < 512) {
        // ================= compute waves =================
        const int lane = tid & 63;
        const int wv   = tid >> 6;       // wave 0..7
        const int g    = lane >> 3;      // output-pair group 0..7
        const int s    = lane & 7;       // K-segment 0..7 (k in [16s,16s+16))
        const int o0   = (wv * 8 + g) * 2;
        const int swz  = s >> 1;         // float4 read-order swizzle

        // W_hh rows o0, o0+1, K-chunk [16s,16s+16), in swizzled j-order
        float w0[16], w1[16];
        {
            const float* r0 = Whh + (size_t)o0 * HH + s * 16;
            const float* r1 = r0 + HH;
#pragma unroll
            for (int j = 0; j < 4; j++) {
                const int jj = (j + swz) & 3;
#pragma unroll
                for (int c = 0; c < 4; c++) {
                    w0[4 * j + c] = r0[4 * jj + c];
                    w1[4 * j + c] = r1[4 * jj + c];
                }
            }
        }
        const float wi00 = Wih[o0 * II + 0], wi01 = Wih[o0 * II + 1],
                    wi02 = Wih[o0 * II + 2];
        const float wi10 = Wih[(o0 + 1) * II + 0], wi11 = Wih[(o0 + 1) * II + 1],
                    wi12 = Wih[(o0 + 1) * II + 2];
        const float bias0 = bih[o0] + bhh[o0];
        const float bias1 = bih[o0 + 1] + bhh[o0 + 1];

        bar_lds();

        auto cstep = [&](int t, const float* hcur, float* hnext) {
            float a0, a1;
            if (s == 0) {
                float4 xv = xs[t];  // 8-lane broadcast
                a0 = fmaf(xv.x, wi00, bias0);
                a0 = fmaf(xv.y, wi01, a0);
                a0 = fmaf(xv.z, wi02, a0);
                a1 = fmaf(xv.x, wi10, bias1);
                a1 = fmaf(xv.y, wi11, a1);
                a1 = fmaf(xv.z, wi12, a1);
            } else {
                a0 = 0.f;
                a1 = 0.f;
            }
            const float4* hr = (const float4*)hcur + s * 4;
            // 4 ds_read_b128; swizzled order -> 8 distinct chunks per issue
            // land on 8 distinct bank groups (conflict-free broadcast).
#pragma unroll
            for (int j = 0; j < 4; j++) {
                const int jj = (j + swz) & 3;
                float4 hh = hr[jj];
                a0 = fmaf(w0[4 * j + 0], hh.x, a0);
                a0 = fmaf(w0[4 * j + 1], hh.y, a0);
                a0 = fmaf(w0[4 * j + 2], hh.z, a0);
                a0 = fmaf(w0[4 * j + 3], hh.w, a0);
                a1 = fmaf(w1[4 * j + 0], hh.x, a1);
                a1 = fmaf(w1[4 * j + 1], hh.y, a1);
                a1 = fmaf(w1[4 * j + 2], hh.z, a1);
                a1 = fmaf(w1[4 * j + 3], hh.w, a1);
            }
            // K-split-8 reduce, DPP-only (no LDS-pipe ops)
            a0 = dpp_add<DPP_XOR1>(a0);
            a0 = dpp_add<DPP_XOR2>(a0);
            a0 = dpp_add<DPP_HALF_MIRROR>(a0);
            a1 = dpp_add<DPP_XOR1>(a1);
            a1 = dpp_add<DPP_XOR2>(a1);
            a1 = dpp_add<DPP_HALF_MIRROR>(a1);
            float th0 = fast_tanh(a0);
            float th1 = fast_tanh(a1);
            if (s == 0) {
                float2 hv;
                hv.x = th0;
                hv.y = th1;
                ((float2*)hnext)[wv * 8 + g] = hv;  // 8 distinct banks per wave
            }
            bar_lds();
        };

        for (int t = 0; t < TT; t += 2) {
            cstep(t, hbuf[0], hbuf[1]);
            cstep(t + 1, hbuf[1], hbuf[0]);
        }
    } else {
        // ================= store + projection wave =================
        const int L = tid - 512;  // lane 0..63; owns h = 2L, 2L+1
        const float w00 = Wout[0 * HH + 2 * L], w01 = Wout[0 * HH + 2 * L + 1];
        const float w10 = Wout[1 * HH + 2 * L], w11 = Wout[1 * HH + 2 * L + 1];
        const float w20 = Wout[2 * HH + 2 * L], w21 = Wout[2 * HH + 2 * L + 1];
        const float bL = (L == 0) ? bout[0] : (L == 1) ? bout[1]
                       : (L == 2) ? bout[2] : 0.f;
        float* ob = out + (size_t)b * TT * OO;
        float* hb = hid + (size_t)b * TT * HH;
        const int q = L >> 2;               // quad id 0..15
        const bool qlead = (L & 3) == 0;

        bar_lds();

        auto sstep = [&](int t, const float* hcur, float* psA, const float* psB) {
            // phase A: hid[t-1] store + quad partials for out[t-1] -> psA
            if (t >= 1) {
                const float2 hv = ((const float2*)hcur)[L];
                ((float2*)(hb + (size_t)(t - 1) * HH))[L] = hv;  // coalesced 512B
                float p0 = fmaf(hv.x, w00, hv.y * w01);
                float p1 = fmaf(hv.x, w10, hv.y * w11);
                float p2 = fmaf(hv.x, w20, hv.y * w21);
                p0 = quad_reduce(p0);
                p1 = quad_reduce(p1);
                p2 = quad_reduce(p2);
                if (qlead) {
                    psA[0 * 16 + q] = p0;
                    psA[1 * 16 + q] = p1;
                    psA[2 * 16 + q] = p2;
                }
            }
            // phase B: finish out[t-2] from previous window's partials (psB).
            if (t >= 2 && L < OO) {
                const float4* pp = (const float4*)(psB + L * 16);
                float4 u0 = pp[0], u1 = pp[1], u2 = pp[2], u3 = pp[3];
                float s0 = ((u0.x + u0.y) + (u0.z + u0.w)) +
                           ((u1.x + u1.y) + (u1.z + u1.w));
                float s1 = ((u2.x + u2.y) + (u2.z + u2.w)) +
                           ((u3.x + u3.y) + (u3.z + u3.w));
                ob[(size_t)(t - 2) * OO + L] = s0 + s1 + bL;
            }
            bar_lds();
        };

        for (int t = 0; t < TT; t += 2) {
            sstep(t, hbuf[0], psum[0], psum[1]);
            sstep(t + 1, hbuf[1], psum[1], psum[0]);
        }

        // tail (no barriers; compute waves exited, barrier counts match):
        // hbuf[0] = h[TT-1], psum[1] holds partials for out[TT-2].
        {
            const float2 hv = ((const float2*)hbuf[0])[L];
            ((float2*)(hb + (size_t)(TT - 1) * HH))[L] = hv;
            float p0 = fmaf(hv.x, w00, hv.y * w01);
            float p1 = fmaf(hv.x, w10, hv.y * w11);
            float p2 = fmaf(hv.x, w20, hv.y * w21);
            p0 = quad_reduce(p0);
            p1 = quad_reduce(p1);
            p2 = quad_reduce(p2);
            if (qlead) {
                psum[0][0 * 16 + q] = p0;
                psum[0][1 * 16 + q] = p1;
                psum[0][2 * 16 + q] = p2;
            }
            if (L < OO) {
                const float4* pp = (const float4*)(psum[1] + L * 16);
                float4 u0 = pp[0], u1 = pp[1], u2 = pp[2], u3 = pp[3];
                float s0 = ((u0.x + u0.y) + (u0.z + u0.w)) +
                           ((u1.x + u1.y) + (u1.z + u1.w));
                float s1 = ((u2.x + u2.y) + (u2.z + u2.w)) +
                           ((u3.x + u3.y) + (u3.z + u3.w));
                ob[(size_t)(TT - 2) * OO + L] = s0 + s1 + bL;
                const float4* pq = (const float4*)(psum[0] + L * 16);
                float4 v0 = pq[0], v1 = pq[1], v2 = pq[2], v3 = pq[3];
                float r0 = ((v0.x + v0.y) + (v0.z + v0.w)) +
                           ((v1.x + v1.y) + (v1.z + v1.w));
                float r1 = ((v2.x + v2.y) + (v2.z + v2.w)) +
                           ((v3.x + v3.y) + (v3.z + v3.w));
                ob[(size_t)(TT - 1) * OO + L] = r0 + r1 + bL;
            }
        }
    }
}

extern "C" void kernel_launch(void* const* d_in, const int* in_sizes, int n_in,
                              void* d_out, int out_size, void* d_ws, size_t ws_size,
                              hipStream_t stream) {
    const float* x    = (const float*)d_in[0];  // [256,1024,3]
    const float* Wih  = (const float*)d_in[1];  // [128,3]
    const float* Whh  = (const float*)d_in[2];  // [128,128]
    const float* bih  = (const float*)d_in[3];  // [128]
    const float* bhh  = (const float*)d_in[4];  // [128]
    const float* h0   = (const float*)d_in[5];  // [1,128]
    const float* Wout = (const float*)d_in[6];  // [3,128]
    const float* bout = (const float*)d_in[7];  // [3]

    float* out = (float*)d_out;                 // [B,T,O] first
    float* hid = out + (size_t)BB * TT * OO;    // then [B,T,H]

    rnn_kernel<<<BB, NT, 0, stream>>>(x, Wih, Whh, bih, bhh, h0, Wout, bout, out, hid);
}